// Round 3
// baseline (1806.445 us; speedup 1.0000x reference)
//
#include <hip/hip_runtime.h>
#include <hip/hip_bf16.h>
#include <stdint.h>

typedef __attribute__((ext_vector_type(8))) short short8;
typedef __attribute__((ext_vector_type(4))) float floatx4;
typedef __attribute__((ext_vector_type(4))) int intx4;
typedef __attribute__((ext_vector_type(2))) unsigned long long ull2;
typedef __attribute__((ext_vector_type(4))) unsigned short ushort4v;

#define DEVI __device__ __forceinline__

// ---- problem sizes ----
constexpr int B_ = 256, T_ = 512, D_ = 128, H_ = 512, C_ = 10;
constexpr int KTOT = H_ + D_;       // 640: k = [h(512) ; x(128)]
constexpr int RG = 16;              // batch rows per group
constexpr int NBG = 16;             // batch groups
constexpr int NCG = 16;             // column groups
constexpr int HCW = 32;             // h-cols per WG

// ---- workspace layout (bytes) ----
constexpr size_t OFF_XB = 0;
constexpr size_t SZ_XB  = (size_t)B_ * T_ * D_ * 2;          // x in bf16
constexpr size_t OFF_WC = OFF_XB + SZ_XB;
constexpr size_t SZ_WC  = (size_t)4 * H_ * KTOT * 2;         // Wcomb[4*H][640] bf16 (transposed)
constexpr size_t OFF_HB = OFF_WC + SZ_WC;
constexpr size_t SZ_HB  = (size_t)2 * B_ * H_ * 2;           // h double buffer bf16
constexpr size_t OFF_CT = OFF_HB + SZ_HB;
constexpr size_t SZ_CT  = (size_t)NBG * (T_ + 1) * 4;        // sync counters
constexpr size_t WS_NEED = OFF_CT + SZ_CT;

DEVI uint16_t f2bf(float f) {
    uint32_t u = __builtin_bit_cast(uint32_t, f);
    u += 0x7FFFu + ((u >> 16) & 1u);
    return (uint16_t)(u >> 16);
}
DEVI float bf2f(uint16_t u) {
    return __builtin_bit_cast(float, (uint32_t)u << 16);
}
DEVI float sigf(float x)  { return 1.0f / (1.0f + __expf(-x)); }
DEVI float tanhf_(float x){ return 1.0f - 2.0f / (1.0f + __expf(2.0f * x)); }

// ---- prep: x fp32 -> bf16 ----
__global__ void k_cvt_x(const float* __restrict__ x, uint16_t* __restrict__ xb) {
    int i = (blockIdx.x * 256 + threadIdx.x) * 4;   // total B*T*D = 16777216
    float4 v = *reinterpret_cast<const float4*>(x + i);
    ushort4v o;
    o.x = f2bf(v.x); o.y = f2bf(v.y); o.z = f2bf(v.z); o.w = f2bf(v.w);
    *reinterpret_cast<ushort4v*>(xb + i) = o;
}

// ---- prep: build combined transposed bf16 weights Wcomb[n'=g*512+n][k] ----
//  k<512 : W?h[k][n] ;  k>=512 : W?x[k-512][n]
__global__ void k_build_w(const float* __restrict__ wgh, const float* __restrict__ wih,
                          const float* __restrict__ wfh, const float* __restrict__ woh,
                          const float* __restrict__ wgx, const float* __restrict__ wix,
                          const float* __restrict__ wfx, const float* __restrict__ wox,
                          uint16_t* __restrict__ wc) {
    int np = blockIdx.x;            // 0..2047
    int g = np >> 9, n = np & 511;
    const float* wh = (g == 0) ? wgh : (g == 1) ? wih : (g == 2) ? wfh : woh;
    const float* wx = (g == 0) ? wgx : (g == 1) ? wix : (g == 2) ? wfx : wox;
    for (int k = threadIdx.x; k < KTOT; k += 256) {
        float v = (k < H_) ? wh[(size_t)k * H_ + n] : wx[(size_t)(k - H_) * H_ + n];
        wc[(size_t)np * KTOT + k] = f2bf(v);
    }
}

// ---- main recurrent kernel ----
// Each WG: 16 batch rows x 32 h-cols. Each WAVE: all 4 gates for 8 h-cols
// (B-tile0 = [g cols | i cols], B-tile1 = [f cols | o cols]) so the gate
// exchange for the cell is 2x shfl_xor(8) in-wave -- no LDS roundtrip.
__global__ __launch_bounds__(256, 1) void k_lstm(
    const uint16_t* __restrict__ xb,   // [B][T][D] bf16
    const uint16_t* __restrict__ wc,   // [4H][KTOT] bf16
    const float* __restrict__ bgp, const float* __restrict__ bip,
    const float* __restrict__ bfp, const float* __restrict__ bop,
    uint16_t* hbuf,                    // [2][B][H] bf16
    int* counters)                     // [NBG][T+1]
{
    __shared__ __align__(16) short hx[RG * KTOT];                 // 20 KB, XOR-swizzled

    const int tid  = threadIdx.x;
    const int lane = tid & 63;
    const int w    = tid >> 6;          // wave id -> col sub-block w*8
    const int bid  = blockIdx.x;
    // keep each batch-group's 16 WGs on one XCD (perf heuristic only)
    const int xcd = bid & 7, j = bid >> 3;
    const int bg = xcd * 2 + (j >> 4);
    const int cg = j & 15;
    const int b0  = bg * RG;
    const int hc0 = cg * HCW;

    // ---- load this wave's weight slice into registers, then PIN them there ----
    // B-frag layout (validated): col = lane&15, k = (lane>>4)*8 + j
    // tile0 col c: c<8 -> gate g col (hc0+w*8+c); c>=8 -> gate i col (hc0+w*8+c-8)
    // tile1: gates f / o same split.
    short8 bf0[20], bf1[20];
    {
        const int lcol = lane & 15, kgrp = lane >> 4;
        const int cl = lcol & 7, hi = lcol >> 3;        // hi: second gate of tile
        const int colg = hc0 + w * 8 + cl;
        const size_t row0 = (size_t)((0 + hi) * H_ + colg) * KTOT;  // g or i
        const size_t row1 = (size_t)((2 + hi) * H_ + colg) * KTOT;  // f or o
        #pragma unroll
        for (int ks = 0; ks < 20; ++ks) {
            bf0[ks] = *reinterpret_cast<const short8*>(wc + row0 + kgrp * 8 + ks * 32);
            bf1[ks] = *reinterpret_cast<const short8*>(wc + row1 + kgrp * 8 + ks * 32);
        }
        #pragma unroll
        for (int ks = 0; ks < 20; ++ks) {
            asm volatile("" : "+v"(bf0[ks]));   // opaque: compiler must keep in VGPRs
            asm volatile("" : "+v"(bf1[ks]));
        }
    }

    // per-lane cell column and biases (lanes c>=8 duplicate partner's col)
    const int cl   = lane & 7;
    const int mycol = hc0 + w * 8 + cl;
    const bool lo  = (lane & 8) == 0;
    const float bgv = bgp[mycol], biv = bip[mycol], bfv = bfp[mycol], bov = bop[mycol];
    float cst[4] = {0.f, 0.f, 0.f, 0.f};       // c-state: 4 rows x 1 col per lane

    // staging mapping: thread -> (row, 64B segment)
    const int srow = tid >> 4, sseg = tid & 15;
    const int sswz = (srow & 7) << 4;
    // A-fragment base (mfma 16x16x32: row = lane&15, k = (lane>>4)*8 + j)
    const int arow = lane & 15, akg = lane >> 4;
    const int abase = arow * (KTOT * 2) + akg * 16;
    const int aswz  = (arow & 7) << 4;
    // h store base row for this lane's 4 rows
    const int hrow0 = (lane >> 4) * 4;

    int* ctr = counters + bg * (T_ + 1);
    char* lds = (char*)hx;

    for (int t = 0; t < T_; ++t) {
        // ---- stage x part (cols 512..639) BEFORE the wait (no h dependence;
        //      prev step's LDS readers passed the post-store barrier) ----
        {
            const short8 xv = *reinterpret_cast<const short8*>(
                xb + ((size_t)(b0 + srow) * T_ + t) * D_ + sseg * 8);
            int byte = srow * (KTOT * 2) + H_ * 2 + sseg * 16;
            *reinterpret_cast<short8*>(lds + (byte ^ sswz)) = xv;
        }

        // ---- wait for h_t from all 16 column groups (RELAXED poll) ----
        if (t > 0) {
            if (tid == 0) {
                int it = 0;
                while (__hip_atomic_load(ctr + t, __ATOMIC_RELAXED, __HIP_MEMORY_SCOPE_AGENT) < NCG) {
                    if (++it > (1 << 28)) break;   // safety: fail loud, not hang
                    __builtin_amdgcn_s_sleep(1);
                }
                asm volatile("" ::: "memory");     // compiler reordering fence only
            }
            __syncthreads();
        }

        // ---- stage h part of A = [h_t ; x_t] into swizzled LDS ----
        if (t == 0) {
            intx4 z = {0, 0, 0, 0};
            #pragma unroll
            for (int c4 = 0; c4 < 4; ++c4) {
                int byte = srow * (KTOT * 2) + sseg * 64 + c4 * 16;
                *reinterpret_cast<intx4*>(lds + (byte ^ sswz)) = z;
            }
        } else {
            const unsigned long long* src = reinterpret_cast<const unsigned long long*>(
                hbuf + (size_t)(t & 1) * B_ * H_ + (size_t)(b0 + srow) * H_ + sseg * 32);
            #pragma unroll
            for (int c4 = 0; c4 < 4; ++c4) {
                unsigned long long lov = __hip_atomic_load(src + c4 * 2,     __ATOMIC_RELAXED, __HIP_MEMORY_SCOPE_AGENT);
                unsigned long long hiv = __hip_atomic_load(src + c4 * 2 + 1, __ATOMIC_RELAXED, __HIP_MEMORY_SCOPE_AGENT);
                ull2 v; v.x = lov; v.y = hiv;
                int byte = srow * (KTOT * 2) + sseg * 64 + c4 * 16;
                *reinterpret_cast<ull2*>(lds + (byte ^ sswz)) = v;
            }
        }
        __syncthreads();

        // ---- MFMA: [16 rows x 16 cols] x 2 tiles, K = 640 ----
        floatx4 acc0 = {0.f, 0.f, 0.f, 0.f}, acc1 = {0.f, 0.f, 0.f, 0.f};
        #pragma unroll
        for (int ks = 0; ks < 20; ++ks) {
            int byte = (abase + ks * 64) ^ aswz;
            short8 a = *reinterpret_cast<const short8*>(lds + byte);
            acc0 = __builtin_amdgcn_mfma_f32_16x16x32_bf16(a, bf0[ks], acc0, 0, 0, 0);
            acc1 = __builtin_amdgcn_mfma_f32_16x16x32_bf16(a, bf1[ks], acc1, 0, 0, 0);
        }

        // ---- gate exchange in-wave + cell update (C layout: col=lane&15, row=(lane>>4)*4+r) ----
        uint16_t hp[4];
        #pragma unroll
        for (int r = 0; r < 4; ++r) {
            float p0 = acc0[r], p1 = acc1[r];
            float q0 = __shfl_xor(p0, 8, 64);
            float q1 = __shfl_xor(p1, 8, 64);
            float ag = (lo ? p0 : q0) + bgv;
            float ai = (lo ? q0 : p0) + biv;
            float af = (lo ? p1 : q1) + bfv;
            float ao = (lo ? q1 : p1) + bov;
            float g = tanhf_(ag), ii = sigf(ai), f = sigf(af), o = sigf(ao);
            float c = g * ii + cst[r] * f;
            cst[r] = c;
            hp[r] = f2bf(tanhf_(c) * o);
        }
        if (lo) {
            uint16_t* hdst = hbuf + (size_t)((t + 1) & 1) * B_ * H_ + (size_t)(b0 + hrow0) * H_ + mycol;
            #pragma unroll
            for (int r = 0; r < 4; ++r)
                __hip_atomic_store(hdst + (size_t)r * H_, hp[r], __ATOMIC_RELAXED, __HIP_MEMORY_SCOPE_AGENT);
        }
        // sc1 stores: vmcnt(0) == visible at device coherence point (no L2 writeback needed)
        asm volatile("s_waitcnt vmcnt(0)" ::: "memory");
        __syncthreads();   // all threads past their waitcnt -> all h stores visible
        if (tid == 0)
            __hip_atomic_fetch_add(ctr + t + 1, 1, __ATOMIC_RELAXED, __HIP_MEMORY_SCOPE_AGENT);
        // next iteration's t>0 wait-barrier protects hx from early overwrite
    }
}

// ---- final projection: out[b][c] = h_T[b] . wph[:,c] + bp[c] ----
__global__ void k_proj(const uint16_t* __restrict__ hb0, const float* __restrict__ wph,
                       const float* __restrict__ bp, float* __restrict__ out) {
    int b = blockIdx.x, lane = threadIdx.x;     // 64 threads
    const uint32_t* hrow = reinterpret_cast<const uint32_t*>(hb0 + (size_t)b * H_);
    float p[C_];
    #pragma unroll
    for (int c = 0; c < C_; ++c) p[c] = 0.f;
    #pragma unroll
    for (int q = 0; q < 4; ++q) {
        int k2 = lane + q * 64;                 // uint32 index 0..255 -> elems 2k2, 2k2+1
        uint32_t u = __hip_atomic_load(hrow + k2, __ATOMIC_RELAXED, __HIP_MEMORY_SCOPE_AGENT);
        float h0 = bf2f((uint16_t)(u & 0xFFFFu));
        float h1 = bf2f((uint16_t)(u >> 16));
        #pragma unroll
        for (int c = 0; c < C_; ++c)
            p[c] += h0 * wph[(size_t)(2 * k2) * C_ + c] + h1 * wph[(size_t)(2 * k2 + 1) * C_ + c];
    }
    #pragma unroll
    for (int c = 0; c < C_; ++c) {
        float v = p[c];
        #pragma unroll
        for (int off = 32; off; off >>= 1) v += __shfl_down(v, off, 64);
        if (lane == 0) out[(size_t)b * C_ + c] = v + bp[c];
    }
}

extern "C" void kernel_launch(void* const* d_in, const int* in_sizes, int n_in,
                              void* d_out, int out_size, void* d_ws, size_t ws_size,
                              hipStream_t stream) {
    const float* x   = (const float*)d_in[0];
    const float* wgx = (const float*)d_in[1];
    const float* wgh = (const float*)d_in[2];
    const float* bg  = (const float*)d_in[3];
    const float* wix = (const float*)d_in[4];
    const float* wih = (const float*)d_in[5];
    const float* bi  = (const float*)d_in[6];
    const float* wfx = (const float*)d_in[7];
    const float* wfh = (const float*)d_in[8];
    const float* bf  = (const float*)d_in[9];
    const float* wox = (const float*)d_in[10];
    const float* woh = (const float*)d_in[11];
    const float* bo  = (const float*)d_in[12];
    const float* wph = (const float*)d_in[13];
    const float* bp  = (const float*)d_in[14];

    if (ws_size < WS_NEED) return;  // fail loud (wrong output) rather than corrupt

    char* ws = (char*)d_ws;
    uint16_t* xbp = (uint16_t*)(ws + OFF_XB);
    uint16_t* wcp = (uint16_t*)(ws + OFF_WC);
    uint16_t* hbp = (uint16_t*)(ws + OFF_HB);
    int*      ctp = (int*)(ws + OFF_CT);

    hipMemsetAsync(ctp, 0, SZ_CT, stream);
    k_cvt_x<<<(B_ * T_ * D_) / (256 * 4), 256, 0, stream>>>(x, xbp);
    k_build_w<<<4 * H_, 256, 0, stream>>>(wgh, wih, wfh, woh, wgx, wix, wfx, wox, wcp);
    k_lstm<<<256, 256, 0, stream>>>(xbp, wcp, bg, bi, bf, bo, hbp, ctp);
    k_proj<<<B_, 64, 0, stream>>>(hbp /* parity 0 holds h_T */, wph, bp, (float*)d_out);
}